// Round 1
// baseline (1461.748 us; speedup 1.0000x reference)
//
#include <hip/hip_runtime.h>
#include <stdint.h>

typedef __attribute__((ext_vector_type(8))) __bf16 bf16x8;
typedef __attribute__((ext_vector_type(4))) float f32x4;

constexpr int B = 8, S = 1024, D = 512, H = 8, DFF = 2048, L = 4, DK = 64;
constexpr int MR = B * S;  // 8192 rows

__device__ __forceinline__ unsigned short f2bf(float f) {
    union { float f; unsigned u; } v; v.f = f;
    unsigned u = v.u;
    u += 0x7fffu + ((u >> 16) & 1u);   // RNE
    return (unsigned short)(u >> 16);
}

// ---------------- x = qe + pe ; y = qa + pe (f32 + bf16 copies) ----------------
__global__ __launch_bounds__(256) void add_pe_kernel(
    const float* __restrict__ qe, const float* __restrict__ qa,
    const float* __restrict__ pe, float* __restrict__ x_f32,
    unsigned short* __restrict__ x_bf, unsigned short* __restrict__ y_bf) {
    int gid = blockIdx.x * 256 + threadIdx.x;
    int base = gid * 4;                      // total MR*D = 4M elems
    int po = base & (S * D - 1);             // S*D is pow2
    float4 p = *(const float4*)(pe + po);
    float4 a = *(const float4*)(qe + base);
    float4 q = *(const float4*)(qa + base);
    float4 xv = make_float4(a.x + p.x, a.y + p.y, a.z + p.z, a.w + p.w);
    float4 yv = make_float4(q.x + p.x, q.y + p.y, q.z + p.z, q.w + p.w);
    *(float4*)(x_f32 + base) = xv;
    ushort4 xb; xb.x = f2bf(xv.x); xb.y = f2bf(xv.y); xb.z = f2bf(xv.z); xb.w = f2bf(xv.w);
    ushort4 yb; yb.x = f2bf(yv.x); yb.y = f2bf(yv.y); yb.z = f2bf(yv.z); yb.w = f2bf(yv.w);
    *(ushort4*)(x_bf + base) = xb;
    *(ushort4*)(y_bf + base) = yb;
}

// ---------------- GEMM: out = act(A[M,K](bf16) @ W[K,N](f32) + bias [+resid]) ----------------
// 128x128 tile, BK=32, 4 waves each computing 64x64 via 4x4 mfma_f32_16x16x32_bf16.
template<bool RELU, bool RESID, bool OUT_F32, bool OUT_BF16>
__global__ __launch_bounds__(256) void gemm_kernel(
    const unsigned short* __restrict__ A, const float* __restrict__ W,
    const float* __restrict__ bias, const float* __restrict__ resid,
    float* __restrict__ out_f32, unsigned short* __restrict__ out_bf,
    int M, int N, int K) {
    __shared__ unsigned short a_lds[128][40];   // [m][k], +8 pad
    __shared__ unsigned short b_lds[128][40];   // [n][k] (W transposed), +8 pad

    const int tid = threadIdx.x;
    const int lane = tid & 63, wid = tid >> 6;
    const int wm = wid >> 1, wn = wid & 1;
    const int l15 = lane & 15, quad = lane >> 4;
    const int bm = blockIdx.x, bn = blockIdx.y;

    f32x4 acc[4][4];
    for (int i = 0; i < 4; i++)
        for (int j = 0; j < 4; j++) { f32x4 z = {0.f, 0.f, 0.f, 0.f}; acc[i][j] = z; }

    const int arow = tid >> 1, ahalf = (tid & 1) * 16;
    const unsigned short* ap = A + (bm * 128 + arow) * K + ahalf;
    const int bk = tid >> 3, bnb = (tid & 7) * 16;
    const float* wp = W + bk * N + bn * 128 + bnb;

    for (int k0 = 0; k0 < K; k0 += 32) {
        // stage A tile (bf16, row-major)
        *(bf16x8*)&a_lds[arow][ahalf]     = *(const bf16x8*)(ap + k0);
        *(bf16x8*)&a_lds[arow][ahalf + 8] = *(const bf16x8*)(ap + k0 + 8);
        // stage W tile transposed, f32 -> bf16
        const float* w0 = wp + k0 * N;
        float4 f0 = *(const float4*)(w0);
        float4 f1 = *(const float4*)(w0 + 4);
        float4 f2 = *(const float4*)(w0 + 8);
        float4 f3 = *(const float4*)(w0 + 12);
        float tmp[16] = {f0.x,f0.y,f0.z,f0.w, f1.x,f1.y,f1.z,f1.w,
                         f2.x,f2.y,f2.z,f2.w, f3.x,f3.y,f3.z,f3.w};
        #pragma unroll
        for (int i = 0; i < 16; i++) b_lds[bnb + i][bk] = f2bf(tmp[i]);
        __syncthreads();

        bf16x8 af[4], bfr[4];
        #pragma unroll
        for (int mt = 0; mt < 4; mt++)
            af[mt] = *(const bf16x8*)&a_lds[wm * 64 + mt * 16 + l15][quad * 8];
        #pragma unroll
        for (int nt = 0; nt < 4; nt++)
            bfr[nt] = *(const bf16x8*)&b_lds[wn * 64 + nt * 16 + l15][quad * 8];
        #pragma unroll
        for (int mt = 0; mt < 4; mt++)
            #pragma unroll
            for (int nt = 0; nt < 4; nt++)
                acc[mt][nt] = __builtin_amdgcn_mfma_f32_16x16x32_bf16(af[mt], bfr[nt], acc[mt][nt], 0, 0, 0);
        __syncthreads();
    }

    // epilogue: C row = quad*4+r, col = lane&15 (per 16x16 frag)
    #pragma unroll
    for (int nt = 0; nt < 4; nt++) {
        int col = bn * 128 + wn * 64 + nt * 16 + l15;
        float bv = bias[col];
        #pragma unroll
        for (int mt = 0; mt < 4; mt++) {
            int row0 = bm * 128 + wm * 64 + mt * 16 + quad * 4;
            #pragma unroll
            for (int r = 0; r < 4; r++) {
                int row = row0 + r;
                float v = acc[mt][nt][r] + bv;
                if (RESID) v += resid[row * N + col];
                if (RELU) v = fmaxf(v, 0.f);
                int o = row * N + col;
                if (OUT_F32) out_f32[o] = v;
                if (OUT_BF16) out_bf[o] = f2bf(v);
            }
        }
    }
}

// ---------------- LayerNorm over D=512, one block per row ----------------
__global__ __launch_bounds__(256) void ln_kernel(
    const float* __restrict__ in, const float* __restrict__ gamma,
    const float* __restrict__ beta, float* __restrict__ out_f32,
    unsigned short* __restrict__ out_bf) {
    __shared__ float red[8];
    int row = blockIdx.x, tid = threadIdx.x;
    const float* p = in + row * D;
    float2 v = *(const float2*)(p + tid * 2);
    float s = v.x + v.y;
    float q = v.x * v.x + v.y * v.y;
    #pragma unroll
    for (int off = 32; off > 0; off >>= 1) {
        s += __shfl_xor(s, off);
        q += __shfl_xor(q, off);
    }
    int wid = tid >> 6, lane = tid & 63;
    if (lane == 0) { red[wid] = s; red[4 + wid] = q; }
    __syncthreads();
    s = red[0] + red[1] + red[2] + red[3];
    q = red[4] + red[5] + red[6] + red[7];
    float mean = s * (1.f / D);
    float var = q * (1.f / D) - mean * mean;
    float inv = rsqrtf(var + 1e-5f);
    int c = tid * 2;
    float2 g = *(const float2*)(gamma + c);
    float2 bb = *(const float2*)(beta + c);
    float o0 = (v.x - mean) * inv * g.x + bb.x;
    float o1 = (v.y - mean) * inv * g.y + bb.y;
    *(float2*)(out_f32 + row * D + c) = make_float2(o0, o1);
    ushort2 ob; ob.x = f2bf(o0); ob.y = f2bf(o1);
    *(ushort2*)(out_bf + row * D + c) = ob;
}

// ---------------- Flash attention: strictly-causal, row0 zeroed, q==k ----------------
// One block per (b, h, 64-row q-tile). 4 waves, each owns 16 q-rows.
__global__ __launch_bounds__(256) void attn_kernel(
    const unsigned short* __restrict__ qk, const unsigned short* __restrict__ vv,
    unsigned short* __restrict__ ob) {
    __shared__ unsigned short q_lds[64][72];
    __shared__ unsigned short k_lds[64][72];
    __shared__ unsigned short vT_lds[64][72];  // vT[d][j] = V[j][d]
    __shared__ unsigned short p_lds[64][72];
    __shared__ float sc_lds[64][68];
    __shared__ float alpha_lds[64];
    __shared__ float l_lds[64];

    int bx = blockIdx.x;
    int qt = bx & 15, h = (bx >> 4) & 7, b = bx >> 7;
    int tid = threadIdx.x, lane = tid & 63, wid = tid >> 6;
    int l15 = lane & 15, quad = lane >> 4;
    int rowbase = b * S;
    int colbase = h * DK;

    {   // stage Q tile
        int j = tid >> 2, c = (tid & 3) * 16;
        const unsigned short* src = qk + (rowbase + qt * 64 + j) * D + colbase + c;
        *(bf16x8*)&q_lds[j][c]     = *(const bf16x8*)(src);
        *(bf16x8*)&q_lds[j][c + 8] = *(const bf16x8*)(src + 8);
    }

    int srow = tid >> 2, sq = tid & 3;  // softmax mapping: 4 threads per q-row
    float m_r = -1e30f, l_r = 0.f;
    f32x4 o_acc[4];
    for (int i = 0; i < 4; i++) { f32x4 z = {0.f, 0.f, 0.f, 0.f}; o_acc[i] = z; }

    for (int kt = 0; kt <= qt; kt++) {
        __syncthreads();
        {   // stage K tile + V tile (transposed)
            int j = tid >> 2, c = (tid & 3) * 16;
            const unsigned short* ks = qk + (rowbase + kt * 64 + j) * D + colbase + c;
            *(bf16x8*)&k_lds[j][c]     = *(const bf16x8*)(ks);
            *(bf16x8*)&k_lds[j][c + 8] = *(const bf16x8*)(ks + 8);
            const unsigned short* vs = vv + (rowbase + kt * 64 + j) * D + colbase + c;
            #pragma unroll
            for (int i = 0; i < 16; i++) vT_lds[c + i][j] = vs[i];
        }
        __syncthreads();

        // scores: wave wid -> rows [wid*16, wid*16+16)
        f32x4 s_acc[4];
        #pragma unroll
        for (int nt = 0; nt < 4; nt++) {
            f32x4 a = {0.f, 0.f, 0.f, 0.f};
            #pragma unroll
            for (int kh = 0; kh < 2; kh++) {
                bf16x8 af = *(const bf16x8*)&q_lds[wid * 16 + l15][kh * 32 + quad * 8];
                bf16x8 bf = *(const bf16x8*)&k_lds[nt * 16 + l15][kh * 32 + quad * 8];
                a = __builtin_amdgcn_mfma_f32_16x16x32_bf16(af, bf, a, 0, 0, 0);
            }
            s_acc[nt] = a;
        }
        #pragma unroll
        for (int nt = 0; nt < 4; nt++)
            #pragma unroll
            for (int r = 0; r < 4; r++)
                sc_lds[wid * 16 + quad * 4 + r][nt * 16 + l15] = s_acc[nt][r];
        __syncthreads();

        // online softmax; thread owns 16 cols of its row
        int gi = qt * 64 + srow;
        float sv[16];
        float mx = -1e30f;
        #pragma unroll
        for (int jj = 0; jj < 16; jj++) {
            int gj = kt * 64 + sq * 16 + jj;
            float sval = sc_lds[srow][sq * 16 + jj] * 0.125f;
            if (gj >= gi) sval = -1e30f;   // strict causal
            sv[jj] = sval;
            mx = fmaxf(mx, sval);
        }
        mx = fmaxf(mx, __shfl_xor(mx, 1));
        mx = fmaxf(mx, __shfl_xor(mx, 2));
        float m_new = fmaxf(m_r, mx);
        float alpha = __expf(m_r - m_new);
        float ls = 0.f;
        #pragma unroll
        for (int jj = 0; jj < 16; jj++) {
            float pv = __expf(sv[jj] - m_new);
            sv[jj] = pv;
            ls += pv;
        }
        ls += __shfl_xor(ls, 1);
        ls += __shfl_xor(ls, 2);
        l_r = l_r * alpha + ls;
        m_r = m_new;
        #pragma unroll
        for (int jj = 0; jj < 16; jj++)
            p_lds[srow][sq * 16 + jj] = f2bf(sv[jj]);
        if (sq == 0) alpha_lds[srow] = alpha;
        __syncthreads();

        // rescale O then PV MFMA
        float al[4];
        #pragma unroll
        for (int r = 0; r < 4; r++) al[r] = alpha_lds[wid * 16 + quad * 4 + r];
        #pragma unroll
        for (int nt = 0; nt < 4; nt++)
            #pragma unroll
            for (int r = 0; r < 4; r++)
                o_acc[nt][r] *= al[r];
        #pragma unroll
        for (int nt = 0; nt < 4; nt++) {
            #pragma unroll
            for (int kh = 0; kh < 2; kh++) {
                bf16x8 af = *(const bf16x8*)&p_lds[wid * 16 + l15][kh * 32 + quad * 8];
                bf16x8 bf = *(const bf16x8*)&vT_lds[nt * 16 + l15][kh * 32 + quad * 8];
                o_acc[nt] = __builtin_amdgcn_mfma_f32_16x16x32_bf16(af, bf, o_acc[nt], 0, 0, 0);
            }
        }
    }

    if (sq == 0) l_lds[srow] = l_r;
    __syncthreads();
    #pragma unroll
    for (int nt = 0; nt < 4; nt++) {
        #pragma unroll
        for (int r = 0; r < 4; r++) {
            int lrow = wid * 16 + quad * 4 + r;
            int si = qt * 64 + lrow;
            float val = o_acc[nt][r] / l_lds[lrow];
            if (si == 0) val = 0.f;        // row_keep
            ob[(rowbase + si) * D + colbase + nt * 16 + l15] = f2bf(val);
        }
    }
}

// ---------------- driver ----------------
extern "C" void kernel_launch(void* const* d_in, const int* in_sizes, int n_in,
                              void* d_out, int out_size, void* d_ws, size_t ws_size,
                              hipStream_t stream) {
    (void)in_sizes; (void)n_in; (void)out_size; (void)ws_size;
    const float* qe  = (const float*)d_in[0];
    const float* qa  = (const float*)d_in[1];
    const float* pe  = (const float*)d_in[2];
    const float* Wk  = (const float*)d_in[3];
    const float* bk  = (const float*)d_in[4];
    const float* Wv  = (const float*)d_in[5];
    const float* bv  = (const float*)d_in[6];
    const float* Wo  = (const float*)d_in[7];
    const float* bo  = (const float*)d_in[8];
    const float* l1s = (const float*)d_in[9];
    const float* l1b = (const float*)d_in[10];
    const float* W1  = (const float*)d_in[11];
    const float* b1  = (const float*)d_in[12];
    const float* W2  = (const float*)d_in[13];
    const float* b2  = (const float*)d_in[14];
    const float* l2s = (const float*)d_in[15];
    const float* l2b = (const float*)d_in[16];

    char* w = (char*)d_ws;
    float* x_f32  = (float*)w;           w += (size_t)MR * D * 4;
    float* t_f32  = (float*)w;           w += (size_t)MR * D * 4;
    float* x1_f32 = (float*)w;           w += (size_t)MR * D * 4;
    unsigned short* x_bf  = (unsigned short*)w; w += (size_t)MR * D * 2;
    unsigned short* y_bf  = (unsigned short*)w; w += (size_t)MR * D * 2;
    unsigned short* qk_bf = (unsigned short*)w; w += (size_t)MR * D * 2;
    unsigned short* v_bf  = (unsigned short*)w; w += (size_t)MR * D * 2;
    unsigned short* o_bf  = (unsigned short*)w; w += (size_t)MR * D * 2;
    unsigned short* x1_bf = (unsigned short*)w; w += (size_t)MR * D * 2;
    unsigned short* h_bf  = (unsigned short*)w; w += (size_t)MR * DFF * 2;

    add_pe_kernel<<<MR * D / 4 / 256, 256, 0, stream>>>(qe, qa, pe, x_f32, x_bf, y_bf);

    dim3 g512(64, 4), g2048(64, 16);
    for (int l = 0; l < L; l++) {
        // q == k (kq_same): one projection
        gemm_kernel<false, false, false, true><<<g512, 256, 0, stream>>>(
            x_bf, Wk + (size_t)l * D * D, bk + l * D, nullptr, nullptr, qk_bf, MR, D, D);
        gemm_kernel<false, false, false, true><<<g512, 256, 0, stream>>>(
            y_bf, Wv + (size_t)l * D * D, bv + l * D, nullptr, nullptr, v_bf, MR, D, D);
        attn_kernel<<<B * H * 16, 256, 0, stream>>>(qk_bf, v_bf, o_bf);
        gemm_kernel<false, true, true, false><<<g512, 256, 0, stream>>>(
            o_bf, Wo + (size_t)l * D * D, bo + l * D, x_f32, t_f32, nullptr, MR, D, D);
        ln_kernel<<<MR, 256, 0, stream>>>(t_f32, l1s + l * D, l1b + l * D, x1_f32, x1_bf);
        gemm_kernel<true, false, false, true><<<g2048, 256, 0, stream>>>(
            x1_bf, W1 + (size_t)l * D * DFF, b1 + l * DFF, nullptr, nullptr, h_bf, MR, DFF, D);
        gemm_kernel<false, true, true, false><<<g512, 256, 0, stream>>>(
            h_bf, W2 + (size_t)l * DFF * D, b2 + l * D, x1_f32, t_f32, nullptr, MR, D, DFF);
        float* xo = (l == L - 1) ? (float*)d_out : x_f32;
        ln_kernel<<<MR, 256, 0, stream>>>(t_f32, l2s + l * D, l2b + l * D, xo, x_bf);
    }
}

// Round 2
// 1047.145 us; speedup vs baseline: 1.3959x; 1.3959x over previous
//
#include <hip/hip_runtime.h>
#include <stdint.h>

typedef __attribute__((ext_vector_type(8))) __bf16 bf16x8;
typedef __attribute__((ext_vector_type(4))) float f32x4;

constexpr int B = 8, S = 1024, D = 512, H = 8, DFF = 2048, L = 4, DK = 64;
constexpr int MR = B * S;  // 8192 rows

__device__ __forceinline__ unsigned short f2bf(float f) {
    union { float f; unsigned u; } v; v.f = f;
    unsigned u = v.u;
    u += 0x7fffu + ((u >> 16) & 1u);   // RNE
    return (unsigned short)(u >> 16);
}

__device__ __forceinline__ void gload_lds16(const void* g, void* l) {
    __builtin_amdgcn_global_load_lds(
        (const __attribute__((address_space(1))) void*)g,
        (__attribute__((address_space(3))) void*)l, 16, 0, 0);
}

// ---------------- x = qe + pe ; y = qa + pe (f32 + bf16 copies) ----------------
__global__ __launch_bounds__(256) void add_pe_kernel(
    const float* __restrict__ qe, const float* __restrict__ qa,
    const float* __restrict__ pe, float* __restrict__ x_f32,
    unsigned short* __restrict__ x_bf, unsigned short* __restrict__ y_bf) {
    int gid = blockIdx.x * 256 + threadIdx.x;
    int base = gid * 4;
    int po = base & (S * D - 1);
    float4 p = *(const float4*)(pe + po);
    float4 a = *(const float4*)(qe + base);
    float4 q = *(const float4*)(qa + base);
    float4 xv = make_float4(a.x + p.x, a.y + p.y, a.z + p.z, a.w + p.w);
    float4 yv = make_float4(q.x + p.x, q.y + p.y, q.z + p.z, q.w + p.w);
    *(float4*)(x_f32 + base) = xv;
    ushort4 xb; xb.x = f2bf(xv.x); xb.y = f2bf(xv.y); xb.z = f2bf(xv.z); xb.w = f2bf(xv.w);
    ushort4 yb; yb.x = f2bf(yv.x); yb.y = f2bf(yv.y); yb.z = f2bf(yv.z); yb.w = f2bf(yv.w);
    *(ushort4*)(x_bf + base) = xb;
    *(ushort4*)(y_bf + base) = yb;
}

// ---------------- weight prep: f32 [K,N] -> bf16 [N,K], per layer (blockIdx.z) ----------------
__global__ __launch_bounds__(256) void wtrans_kernel(
    const float* __restrict__ src, unsigned short* __restrict__ dst, int K, int N) {
    __shared__ float t[64][65];
    src += (size_t)blockIdx.z * K * N;
    dst += (size_t)blockIdx.z * K * N;
    int n0 = blockIdx.x * 64, k0 = blockIdx.y * 64;
    int tid = threadIdx.x;
    int r = tid >> 4, c4 = (tid & 15) * 4;
    #pragma unroll
    for (int rr = 0; rr < 64; rr += 16) {
        float4 v = *(const float4*)(src + (size_t)(k0 + r + rr) * N + n0 + c4);
        t[r + rr][c4] = v.x; t[r + rr][c4 + 1] = v.y;
        t[r + rr][c4 + 2] = v.z; t[r + rr][c4 + 3] = v.w;
    }
    __syncthreads();
    int n = tid >> 2, kc = (tid & 3) * 16;
    ushort4 o[4];
    #pragma unroll
    for (int g = 0; g < 4; g++) {
        o[g].x = f2bf(t[kc + g * 4 + 0][n]);
        o[g].y = f2bf(t[kc + g * 4 + 1][n]);
        o[g].z = f2bf(t[kc + g * 4 + 2][n]);
        o[g].w = f2bf(t[kc + g * 4 + 3][n]);
    }
    unsigned short* dp = dst + (size_t)(n0 + n) * K + k0 + kc;
    #pragma unroll
    for (int g = 0; g < 4; g++) *(ushort4*)(dp + g * 4) = o[g];
}

// ---------------- GEMM: out = act(A[M,K](bf16) @ Bt[N,K](bf16)^T + bias [+resid]) ----------------
// 128x128 tile, BK=32, global_load_lds width-16 staging, XOR-swizzled unpadded LDS.
template<bool RELU, bool RESID, bool OUT_F32, bool OUT_BF16>
__global__ __launch_bounds__(256) void gemm_kernel(
    const unsigned short* __restrict__ A, const unsigned short* __restrict__ Bt,
    const float* __restrict__ bias, const float* __restrict__ resid,
    float* __restrict__ out_f32, unsigned short* __restrict__ out_bf,
    int M, int N, int K) {
    __shared__ unsigned short a_lds[128 * 32];
    __shared__ unsigned short b_lds[128 * 32];

    const int tid = threadIdx.x;
    const int lane = tid & 63, wid = tid >> 6;
    const int wm = wid >> 1, wn = wid & 1;
    const int l15 = lane & 15, quad = lane >> 4;
    const int m0 = blockIdx.x * 128, n0 = blockIdx.y * 128;

    f32x4 acc[4][4];
    #pragma unroll
    for (int i = 0; i < 4; i++)
        #pragma unroll
        for (int j = 0; j < 4; j++) { f32x4 z = {0.f, 0.f, 0.f, 0.f}; acc[i][j] = z; }

    // staging: 512 16-B chunks per tile; wave w covers chunks [w*128, w*128+128)
    // chunk c -> LDS byte c*16; logical (row=c>>2, kg=(c&3)^(row&3))
    const int c0 = wid * 128 + lane, c1 = c0 + 64;
    const int r0 = c0 >> 2, kga0 = (c0 & 3) ^ (r0 & 3);
    const int r1 = c1 >> 2, kga1 = (c1 & 3) ^ (r1 & 3);
    const unsigned short* aP0 = A + (size_t)(m0 + r0) * K + kga0 * 8;
    const unsigned short* aP1 = A + (size_t)(m0 + r1) * K + kga1 * 8;
    const unsigned short* bP0 = Bt + (size_t)(n0 + r0) * K + kga0 * 8;
    const unsigned short* bP1 = Bt + (size_t)(n0 + r1) * K + kga1 * 8;
    unsigned short* aL0 = a_lds + wid * 1024;   // wave-uniform
    unsigned short* aL1 = aL0 + 512;
    unsigned short* bL0 = b_lds + wid * 1024;
    unsigned short* bL1 = bL0 + 512;

    for (int k0 = 0; k0 < K; k0 += 32) {
        gload_lds16(aP0 + k0, aL0);
        gload_lds16(aP1 + k0, aL1);
        gload_lds16(bP0 + k0, bL0);
        gload_lds16(bP1 + k0, bL1);
        __syncthreads();

        bf16x8 af[4], bfv[4];
        #pragma unroll
        for (int mt = 0; mt < 4; mt++) {
            int row = wm * 64 + mt * 16 + l15;
            af[mt] = *(const bf16x8*)&a_lds[row * 32 + ((quad ^ (row & 3)) * 8)];
        }
        #pragma unroll
        for (int nt = 0; nt < 4; nt++) {
            int row = wn * 64 + nt * 16 + l15;
            bfv[nt] = *(const bf16x8*)&b_lds[row * 32 + ((quad ^ (row & 3)) * 8)];
        }
        #pragma unroll
        for (int mt = 0; mt < 4; mt++)
            #pragma unroll
            for (int nt = 0; nt < 4; nt++)
                acc[mt][nt] = __builtin_amdgcn_mfma_f32_16x16x32_bf16(af[mt], bfv[nt], acc[mt][nt], 0, 0, 0);
        __syncthreads();
    }

    #pragma unroll
    for (int nt = 0; nt < 4; nt++) {
        int col = n0 + wn * 64 + nt * 16 + l15;
        float bv = bias[col];
        #pragma unroll
        for (int mt = 0; mt < 4; mt++) {
            int row0 = m0 + wm * 64 + mt * 16 + quad * 4;
            #pragma unroll
            for (int r = 0; r < 4; r++) {
                int row = row0 + r;
                float v = acc[mt][nt][r] + bv;
                if (RESID) v += resid[(size_t)row * N + col];
                if (RELU) v = fmaxf(v, 0.f);
                size_t o = (size_t)row * N + col;
                if (OUT_F32) out_f32[o] = v;
                if (OUT_BF16) out_bf[o] = f2bf(v);
            }
        }
    }
}

// ---------------- LayerNorm over D=512, one block per row ----------------
__global__ __launch_bounds__(256) void ln_kernel(
    const float* __restrict__ in, const float* __restrict__ gamma,
    const float* __restrict__ beta, float* __restrict__ out_f32,
    unsigned short* __restrict__ out_bf) {
    __shared__ float red[8];
    int row = blockIdx.x, tid = threadIdx.x;
    const float* p = in + (size_t)row * D;
    float2 v = *(const float2*)(p + tid * 2);
    float s = v.x + v.y;
    float q = v.x * v.x + v.y * v.y;
    #pragma unroll
    for (int off = 32; off > 0; off >>= 1) {
        s += __shfl_xor(s, off);
        q += __shfl_xor(q, off);
    }
    int wid = tid >> 6, lane = tid & 63;
    if (lane == 0) { red[wid] = s; red[4 + wid] = q; }
    __syncthreads();
    s = red[0] + red[1] + red[2] + red[3];
    q = red[4] + red[5] + red[6] + red[7];
    float mean = s * (1.f / D);
    float var = q * (1.f / D) - mean * mean;
    float inv = rsqrtf(var + 1e-5f);
    int c = tid * 2;
    float2 g = *(const float2*)(gamma + c);
    float2 bb = *(const float2*)(beta + c);
    float o0 = (v.x - mean) * inv * g.x + bb.x;
    float o1 = (v.y - mean) * inv * g.y + bb.y;
    *(float2*)(out_f32 + (size_t)row * D + c) = make_float2(o0, o1);
    ushort2 ob; ob.x = f2bf(o0); ob.y = f2bf(o1);
    *(ushort2*)(out_bf + (size_t)row * D + c) = ob;
}

// ---------------- Flash attention: strictly-causal, row0 zeroed, q==k ----------------
__global__ __launch_bounds__(256) void attn_kernel(
    const unsigned short* __restrict__ qk, const unsigned short* __restrict__ vv,
    unsigned short* __restrict__ ob) {
    __shared__ unsigned short q_lds[64][72];
    __shared__ unsigned short k_lds[64][72];
    __shared__ unsigned short vT_lds[64][72];
    __shared__ unsigned short p_lds[64][72];
    __shared__ float sc_lds[64][68];
    __shared__ float alpha_lds[64];
    __shared__ float l_lds[64];

    int bx = blockIdx.x;
    int qt = bx & 15, h = (bx >> 4) & 7, b = bx >> 7;
    int tid = threadIdx.x, lane = tid & 63, wid = tid >> 6;
    int l15 = lane & 15, quad = lane >> 4;
    int rowbase = b * S;
    int colbase = h * DK;

    {
        int j = tid >> 2, c = (tid & 3) * 16;
        const unsigned short* src = qk + (size_t)(rowbase + qt * 64 + j) * D + colbase + c;
        *(bf16x8*)&q_lds[j][c]     = *(const bf16x8*)(src);
        *(bf16x8*)&q_lds[j][c + 8] = *(const bf16x8*)(src + 8);
    }

    int srow = tid >> 2, sq = tid & 3;
    float m_r = -1e30f, l_r = 0.f;
    f32x4 o_acc[4];
    #pragma unroll
    for (int i = 0; i < 4; i++) { f32x4 z = {0.f, 0.f, 0.f, 0.f}; o_acc[i] = z; }

    for (int kt = 0; kt <= qt; kt++) {
        __syncthreads();
        {
            int j = tid >> 2, c = (tid & 3) * 16;
            const unsigned short* ks = qk + (size_t)(rowbase + kt * 64 + j) * D + colbase + c;
            *(bf16x8*)&k_lds[j][c]     = *(const bf16x8*)(ks);
            *(bf16x8*)&k_lds[j][c + 8] = *(const bf16x8*)(ks + 8);
            const unsigned short* vs = vv + (size_t)(rowbase + kt * 64 + j) * D + colbase + c;
            #pragma unroll
            for (int i = 0; i < 16; i++) vT_lds[c + i][j] = vs[i];
        }
        __syncthreads();

        f32x4 s_acc[4];
        #pragma unroll
        for (int nt = 0; nt < 4; nt++) {
            f32x4 a = {0.f, 0.f, 0.f, 0.f};
            #pragma unroll
            for (int kh = 0; kh < 2; kh++) {
                bf16x8 af = *(const bf16x8*)&q_lds[wid * 16 + l15][kh * 32 + quad * 8];
                bf16x8 bf = *(const bf16x8*)&k_lds[nt * 16 + l15][kh * 32 + quad * 8];
                a = __builtin_amdgcn_mfma_f32_16x16x32_bf16(af, bf, a, 0, 0, 0);
            }
            s_acc[nt] = a;
        }
        #pragma unroll
        for (int nt = 0; nt < 4; nt++)
            #pragma unroll
            for (int r = 0; r < 4; r++)
                sc_lds[wid * 16 + quad * 4 + r][nt * 16 + l15] = s_acc[nt][r];
        __syncthreads();

        int gi = qt * 64 + srow;
        float sv[16];
        float mx = -1e30f;
        #pragma unroll
        for (int jj = 0; jj < 16; jj++) {
            int gj = kt * 64 + sq * 16 + jj;
            float sval = sc_lds[srow][sq * 16 + jj] * 0.125f;
            if (gj >= gi) sval = -1e30f;
            sv[jj] = sval;
            mx = fmaxf(mx, sval);
        }
        mx = fmaxf(mx, __shfl_xor(mx, 1));
        mx = fmaxf(mx, __shfl_xor(mx, 2));
        float m_new = fmaxf(m_r, mx);
        float alpha = __expf(m_r - m_new);
        float ls = 0.f;
        #pragma unroll
        for (int jj = 0; jj < 16; jj++) {
            float pv = __expf(sv[jj] - m_new);
            sv[jj] = pv;
            ls += pv;
        }
        ls += __shfl_xor(ls, 1);
        ls += __shfl_xor(ls, 2);
        l_r = l_r * alpha + ls;
        m_r = m_new;
        #pragma unroll
        for (int jj = 0; jj < 16; jj++)
            p_lds[srow][sq * 16 + jj] = f2bf(sv[jj]);
        if (sq == 0) alpha_lds[srow] = alpha;
        __syncthreads();

        float al[4];
        #pragma unroll
        for (int r = 0; r < 4; r++) al[r] = alpha_lds[wid * 16 + quad * 4 + r];
        #pragma unroll
        for (int nt = 0; nt < 4; nt++)
            #pragma unroll
            for (int r = 0; r < 4; r++)
                o_acc[nt][r] *= al[r];
        #pragma unroll
        for (int nt = 0; nt < 4; nt++) {
            #pragma unroll
            for (int kh = 0; kh < 2; kh++) {
                bf16x8 af = *(const bf16x8*)&p_lds[wid * 16 + l15][kh * 32 + quad * 8];
                bf16x8 bf = *(const bf16x8*)&vT_lds[nt * 16 + l15][kh * 32 + quad * 8];
                o_acc[nt] = __builtin_amdgcn_mfma_f32_16x16x32_bf16(af, bf, o_acc[nt], 0, 0, 0);
            }
        }
    }

    if (sq == 0) l_lds[srow] = l_r;
    __syncthreads();
    #pragma unroll
    for (int nt = 0; nt < 4; nt++) {
        #pragma unroll
        for (int r = 0; r < 4; r++) {
            int lrow = wid * 16 + quad * 4 + r;
            int si = qt * 64 + lrow;
            float val = o_acc[nt][r] / l_lds[lrow];
            if (si == 0) val = 0.f;
            ob[(size_t)(rowbase + si) * D + colbase + nt * 16 + l15] = f2bf(val);
        }
    }
}

// ---------------- driver ----------------
extern "C" void kernel_launch(void* const* d_in, const int* in_sizes, int n_in,
                              void* d_out, int out_size, void* d_ws, size_t ws_size,
                              hipStream_t stream) {
    (void)in_sizes; (void)n_in; (void)out_size; (void)ws_size;
    const float* qe  = (const float*)d_in[0];
    const float* qa  = (const float*)d_in[1];
    const float* pe  = (const float*)d_in[2];
    const float* Wk  = (const float*)d_in[3];
    const float* bk  = (const float*)d_in[4];
    const float* Wv  = (const float*)d_in[5];
    const float* bv  = (const float*)d_in[6];
    const float* Wo  = (const float*)d_in[7];
    const float* bo  = (const float*)d_in[8];
    const float* l1s = (const float*)d_in[9];
    const float* l1b = (const float*)d_in[10];
    const float* W1  = (const float*)d_in[11];
    const float* b1  = (const float*)d_in[12];
    const float* W2  = (const float*)d_in[13];
    const float* b2  = (const float*)d_in[14];
    const float* l2s = (const float*)d_in[15];
    const float* l2b = (const float*)d_in[16];

    char* w = (char*)d_ws;
    float* x_f32  = (float*)w;           w += (size_t)MR * D * 4;
    float* t_f32  = (float*)w;           w += (size_t)MR * D * 4;
    float* x1_f32 = (float*)w;           w += (size_t)MR * D * 4;
    unsigned short* x_bf  = (unsigned short*)w; w += (size_t)MR * D * 2;
    unsigned short* y_bf  = (unsigned short*)w; w += (size_t)MR * D * 2;
    unsigned short* qk_bf = (unsigned short*)w; w += (size_t)MR * D * 2;
    unsigned short* v_bf  = (unsigned short*)w; w += (size_t)MR * D * 2;
    unsigned short* o_bf  = (unsigned short*)w; w += (size_t)MR * D * 2;
    unsigned short* x1_bf = (unsigned short*)w; w += (size_t)MR * D * 2;
    unsigned short* h_bf  = (unsigned short*)w; w += (size_t)MR * DFF * 2;
    unsigned short* wkT = (unsigned short*)w;   w += (size_t)L * D * D * 2;
    unsigned short* wvT = (unsigned short*)w;   w += (size_t)L * D * D * 2;
    unsigned short* woT = (unsigned short*)w;   w += (size_t)L * D * D * 2;
    unsigned short* w1T = (unsigned short*)w;   w += (size_t)L * D * DFF * 2;
    unsigned short* w2T = (unsigned short*)w;   w += (size_t)L * DFF * D * 2;

    add_pe_kernel<<<MR * D / 4 / 256, 256, 0, stream>>>(qe, qa, pe, x_f32, x_bf, y_bf);
    wtrans_kernel<<<dim3(8, 8, L), 256, 0, stream>>>(Wk, wkT, D, D);
    wtrans_kernel<<<dim3(8, 8, L), 256, 0, stream>>>(Wv, wvT, D, D);
    wtrans_kernel<<<dim3(8, 8, L), 256, 0, stream>>>(Wo, woT, D, D);
    wtrans_kernel<<<dim3(32, 8, L), 256, 0, stream>>>(W1, w1T, D, DFF);
    wtrans_kernel<<<dim3(8, 32, L), 256, 0, stream>>>(W2, w2T, DFF, D);

    dim3 g512(64, 4), g2048(64, 16);
    for (int l = 0; l < L; l++) {
        gemm_kernel<false, false, false, true><<<g512, 256, 0, stream>>>(
            x_bf, wkT + (size_t)l * D * D, bk + l * D, nullptr, nullptr, qk_bf, MR, D, D);
        gemm_kernel<false, false, false, true><<<g512, 256, 0, stream>>>(
            y_bf, wvT + (size_t)l * D * D, bv + l * D, nullptr, nullptr, v_bf, MR, D, D);
        attn_kernel<<<B * H * 16, 256, 0, stream>>>(qk_bf, v_bf, o_bf);
        gemm_kernel<false, true, true, false><<<g512, 256, 0, stream>>>(
            o_bf, woT + (size_t)l * D * D, bo + l * D, x_f32, t_f32, nullptr, MR, D, D);
        ln_kernel<<<MR, 256, 0, stream>>>(t_f32, l1s + l * D, l1b + l * D, x1_f32, x1_bf);
        gemm_kernel<true, false, false, true><<<g2048, 256, 0, stream>>>(
            x1_bf, w1T + (size_t)l * D * DFF, b1 + l * DFF, nullptr, nullptr, h_bf, MR, DFF, D);
        gemm_kernel<false, true, true, false><<<g512, 256, 0, stream>>>(
            h_bf, w2T + (size_t)l * DFF * D, b2 + l * D, x1_f32, t_f32, nullptr, MR, D, DFF);
        float* xo = (l == L - 1) ? (float*)d_out : x_f32;
        ln_kernel<<<MR, 256, 0, stream>>>(t_f32, l2s + l * D, l2b + l * D, xo, x_bf);
    }
}